// Round 1
// baseline (720.921 us; speedup 1.0000x reference)
//
#include <hip/hip_runtime.h>

// GCN: out = Ahat*(relu(Ahat*(x@W1)+b1))@W2 + b2,  Ahat = D^-1/2 (A+I) D^-1/2
// N=100000, E=1600000, IN=256, HID=128, OUT=64, all fp32.
// Structure: build CSR-by-dst once (deg -> scan -> fill), then per layer:
//   GEMM (fp32, 64x64 tile, 4x4/thread)  ->  per-node wave gather-aggregate.

#define IN_DIM 256
#define HID_DIM 128
#define OUT_DIM 64
#define SCAN_BS 512

__global__ __launch_bounds__(256) void deg_kernel(const int* __restrict__ dst, int E,
                                                  int* __restrict__ deg) {
  int i = blockIdx.x * 256 + threadIdx.x;
  if (i < E) atomicAdd(&deg[dst[i]], 1);
}

// Block-level exclusive scan of deg into off; block totals to bsum; also dinv.
__global__ __launch_bounds__(SCAN_BS) void scan_a_kernel(const int* __restrict__ deg, int N,
                                                         int* __restrict__ off,
                                                         int* __restrict__ bsum,
                                                         float* __restrict__ dinv) {
  __shared__ int sh[SCAN_BS];
  int t = threadIdx.x;
  int g = blockIdx.x * SCAN_BS + t;
  int v = (g < N) ? deg[g] : 0;
  if (g < N) dinv[g] = 1.0f / sqrtf((float)(v + 1));  // self-loop => deg+1 >= 1
  sh[t] = v;
  __syncthreads();
  for (int s = 1; s < SCAN_BS; s <<= 1) {
    int add = (t >= s) ? sh[t - s] : 0;
    __syncthreads();
    sh[t] += add;
    __syncthreads();
  }
  if (g < N) off[g] = sh[t] - v;  // exclusive within block
  if (t == SCAN_BS - 1) bsum[blockIdx.x] = sh[t];
}

// Scan block sums (nb <= 256 for N <= 131072).
__global__ __launch_bounds__(256) void scan_b_kernel(int* __restrict__ bsum, int nb) {
  __shared__ int sh[256];
  int t = threadIdx.x;
  int v = (t < nb) ? bsum[t] : 0;
  sh[t] = v;
  __syncthreads();
  for (int s = 1; s < 256; s <<= 1) {
    int add = (t >= s) ? sh[t - s] : 0;
    __syncthreads();
    sh[t] += add;
    __syncthreads();
  }
  if (t < nb) bsum[t] = sh[t] - v;  // exclusive block offsets
}

__global__ __launch_bounds__(256) void scan_c_kernel(int* __restrict__ off,
                                                     const int* __restrict__ bsum,
                                                     int N, int E) {
  int g = blockIdx.x * 256 + threadIdx.x;
  if (g < N) off[g] += bsum[g / SCAN_BS];
  if (g == 0) off[N] = E;
}

// Scatter edges into CSR slots; payload = (src, dinv[src] bitcast).
__global__ __launch_bounds__(256) void fill_kernel(const int* __restrict__ src,
                                                   const int* __restrict__ dst, int E,
                                                   const int* __restrict__ off,
                                                   int* __restrict__ cursor,
                                                   const float* __restrict__ dinv,
                                                   int2* __restrict__ csr) {
  int i = blockIdx.x * 256 + threadIdx.x;
  if (i >= E) return;
  int d = dst[i], s = src[i];
  int p = off[d] + atomicAdd(&cursor[d], 1);
  csr[p] = make_int2(s, __float_as_int(dinv[s]));
}

// C[M x NC] = A[M x K] @ W[K x NC].  64x64 tile per 256-thread block, 4x4/thread.
template <int K, int NC>
__global__ __launch_bounds__(256) void gemm_kernel(const float* __restrict__ A,
                                                   const float* __restrict__ W,
                                                   float* __restrict__ C, int M) {
  __shared__ float xT[16][64];  // [kk][r]  (transposed so inner reads are b128)
  __shared__ float ws[16][64];  // [kk][c]
  int row0 = blockIdx.x * 64;
  int c0 = blockIdx.y * 64;
  int t = threadIdx.x;
  int rt = t >> 4;       // 0..15 -> rows rt*4..rt*4+3
  int ct = t & 15;       // 0..15 -> cols ct*4..ct*4+3
  int lr = t >> 2;       // x-load row 0..63
  int lk = (t & 3) * 4;  // x-load k offset 0,4,8,12
  int wk = t >> 4;       // W-load k 0..15
  int wc = (t & 15) * 4; // W-load col 0..60
  float acc[4][4] = {};
  for (int k0 = 0; k0 < K; k0 += 16) {
    float4 xv = make_float4(0.f, 0.f, 0.f, 0.f);
    int grow = row0 + lr;
    if (grow < M) xv = *(const float4*)(A + (size_t)grow * K + k0 + lk);
    float4 wv = *(const float4*)(W + (size_t)(k0 + wk) * NC + c0 + wc);
    xT[lk + 0][lr] = xv.x;
    xT[lk + 1][lr] = xv.y;
    xT[lk + 2][lr] = xv.z;
    xT[lk + 3][lr] = xv.w;
    *(float4*)&ws[wk][wc] = wv;
    __syncthreads();
#pragma unroll
    for (int kk = 0; kk < 16; kk++) {
      float4 a4 = *(const float4*)&xT[kk][rt * 4];
      float4 b4 = *(const float4*)&ws[kk][ct * 4];
      acc[0][0] += a4.x * b4.x; acc[0][1] += a4.x * b4.y;
      acc[0][2] += a4.x * b4.z; acc[0][3] += a4.x * b4.w;
      acc[1][0] += a4.y * b4.x; acc[1][1] += a4.y * b4.y;
      acc[1][2] += a4.y * b4.z; acc[1][3] += a4.y * b4.w;
      acc[2][0] += a4.z * b4.x; acc[2][1] += a4.z * b4.y;
      acc[2][2] += a4.z * b4.z; acc[2][3] += a4.z * b4.w;
      acc[3][0] += a4.w * b4.x; acc[3][1] += a4.w * b4.y;
      acc[3][2] += a4.w * b4.z; acc[3][3] += a4.w * b4.w;
    }
    __syncthreads();
  }
#pragma unroll
  for (int i = 0; i < 4; i++) {
    int row = row0 + rt * 4 + i;
    if (row < M)
      *(float4*)(C + (size_t)row * NC + c0 + ct * 4) =
          make_float4(acc[i][0], acc[i][1], acc[i][2], acc[i][3]);
  }
}

// One wave per node: out[n,:] = dinv[n]*(sum_e w_e*h[src_e,:]) + dinv[n]^2*h[n,:] + b
// VW = floats per lane (NC = 64*VW).
template <int NC, int VW, bool RELU>
__global__ __launch_bounds__(256) void agg_kernel(const float* __restrict__ h,
                                                  const int* __restrict__ off,
                                                  const int2* __restrict__ csr,
                                                  const float* __restrict__ dinv,
                                                  const float* __restrict__ bias,
                                                  float* __restrict__ out, int N) {
  int node = blockIdx.x * 4 + (threadIdx.x >> 6);
  int lane = threadIdx.x & 63;
  if (node >= N) return;
  int c = lane * VW;
  float di = dinv[node];
  float acc[VW];
  const float* hrow = h + (size_t)node * NC + c;
#pragma unroll
  for (int j = 0; j < VW; j++) acc[j] = di * hrow[j];  // self-loop (x di again below)
  int e0 = off[node], e1 = off[node + 1];
  for (int e = e0; e < e1; e++) {
    int2 sw = csr[e];
    float w = __int_as_float(sw.y);  // dinv[src]
    const float* hs = h + (size_t)sw.x * NC + c;
#pragma unroll
    for (int j = 0; j < VW; j++) acc[j] += w * hs[j];
  }
#pragma unroll
  for (int j = 0; j < VW; j++) {
    float r = di * acc[j] + bias[c + j];
    if (RELU) r = fmaxf(r, 0.f);
    out[(size_t)node * NC + c + j] = r;
  }
}

extern "C" void kernel_launch(void* const* d_in, const int* in_sizes, int n_in,
                              void* d_out, int out_size, void* d_ws, size_t ws_size,
                              hipStream_t stream) {
  const float* x  = (const float*)d_in[0];
  const int*   ei = (const int*)d_in[1];
  const float* W1 = (const float*)d_in[2];
  const float* b1 = (const float*)d_in[3];
  const float* W2 = (const float*)d_in[4];
  const float* b2 = (const float*)d_in[5];
  float* out = (float*)d_out;

  int N = in_sizes[0] / IN_DIM;
  int E = in_sizes[1] / 2;
  const int* src = ei;       // edge_index[0]
  const int* dst = ei + E;   // edge_index[1]

  // workspace carve-up (256B aligned); total ~117 MB
  char* p = (char*)d_ws;
  auto alloc = [&](size_t bytes) {
    char* q = p;
    p += (bytes + 255) & ~(size_t)255;
    return q;
  };
  int*   deg    = (int*)alloc((size_t)N * 4);
  float* dinv   = (float*)alloc((size_t)N * 4);
  int*   off    = (int*)alloc((size_t)(N + 1) * 4);
  int*   bsum   = (int*)alloc(256 * 4);
  int*   cursor = (int*)alloc((size_t)N * 4);
  int2*  csr    = (int2*)alloc((size_t)E * 8);
  float* h1     = (float*)alloc((size_t)N * HID_DIM * 4);  // reused as h2 (smaller)
  float* z      = (float*)alloc((size_t)N * HID_DIM * 4);
  float* h2     = h1;
  (void)ws_size; (void)n_in; (void)out_size;

  hipMemsetAsync(deg, 0, (size_t)N * 4, stream);
  hipMemsetAsync(cursor, 0, (size_t)N * 4, stream);

  int eb = (E + 255) / 256;
  deg_kernel<<<eb, 256, 0, stream>>>(dst, E, deg);
  int nb = (N + SCAN_BS - 1) / SCAN_BS;  // 196 for N=100000 (<=256 required)
  scan_a_kernel<<<nb, SCAN_BS, 0, stream>>>(deg, N, off, bsum, dinv);
  scan_b_kernel<<<1, 256, 0, stream>>>(bsum, nb);
  scan_c_kernel<<<(N + 255) / 256, 256, 0, stream>>>(off, bsum, N, E);
  fill_kernel<<<eb, 256, 0, stream>>>(src, dst, E, off, cursor, dinv, csr);

  dim3 g1((N + 63) / 64, HID_DIM / 64);
  gemm_kernel<IN_DIM, HID_DIM><<<g1, 256, 0, stream>>>(x, W1, h1, N);
  agg_kernel<HID_DIM, 2, true><<<(N + 3) / 4, 256, 0, stream>>>(h1, off, csr, dinv, b1, z, N);

  dim3 g2((N + 63) / 64, OUT_DIM / 64);
  gemm_kernel<HID_DIM, OUT_DIM><<<g2, 256, 0, stream>>>(z, W2, h2, N);
  agg_kernel<OUT_DIM, 1, false><<<(N + 3) / 4, 256, 0, stream>>>(h2, off, csr, dinv, b2, out, N);
}

// Round 2
// 606.723 us; speedup vs baseline: 1.1882x; 1.1882x over previous
//
#include <hip/hip_runtime.h>
#include <hip/hip_fp16.h>

// GCN: out = Ahat*(relu(Ahat*(x@W1)+b1))@W2 + b2,  Ahat = D^-1/2 (A+I) D^-1/2
// N=100000, E=1600000, IN=256, HID=128, OUT=64, fp32 in/out.
// R2: h1/h2 stored fp16 (halves gather traffic; fp16 eps 4.9e-4 keeps error
//     well under the 1.0e-2 threshold); GEMM upgraded to 128x128 tile, 8x8
//     per thread (VALU-roofline-bound); agg edge loop unrolled x2.

#define IN_DIM 256
#define HID_DIM 128
#define OUT_DIM 64
#define SCAN_BS 512

__global__ __launch_bounds__(256) void deg_kernel(const int* __restrict__ dst, int E,
                                                  int* __restrict__ deg) {
  int i = blockIdx.x * 256 + threadIdx.x;
  if (i < E) atomicAdd(&deg[dst[i]], 1);
}

// Block-level exclusive scan of deg into off; block totals to bsum; also dinv.
__global__ __launch_bounds__(SCAN_BS) void scan_a_kernel(const int* __restrict__ deg, int N,
                                                         int* __restrict__ off,
                                                         int* __restrict__ bsum,
                                                         float* __restrict__ dinv) {
  __shared__ int sh[SCAN_BS];
  int t = threadIdx.x;
  int g = blockIdx.x * SCAN_BS + t;
  int v = (g < N) ? deg[g] : 0;
  if (g < N) dinv[g] = 1.0f / sqrtf((float)(v + 1));  // self-loop => deg+1 >= 1
  sh[t] = v;
  __syncthreads();
  for (int s = 1; s < SCAN_BS; s <<= 1) {
    int add = (t >= s) ? sh[t - s] : 0;
    __syncthreads();
    sh[t] += add;
    __syncthreads();
  }
  if (g < N) off[g] = sh[t] - v;  // exclusive within block
  if (t == SCAN_BS - 1) bsum[blockIdx.x] = sh[t];
}

__global__ __launch_bounds__(256) void scan_b_kernel(int* __restrict__ bsum, int nb) {
  __shared__ int sh[256];
  int t = threadIdx.x;
  int v = (t < nb) ? bsum[t] : 0;
  sh[t] = v;
  __syncthreads();
  for (int s = 1; s < 256; s <<= 1) {
    int add = (t >= s) ? sh[t - s] : 0;
    __syncthreads();
    sh[t] += add;
    __syncthreads();
  }
  if (t < nb) bsum[t] = sh[t] - v;  // exclusive block offsets
}

__global__ __launch_bounds__(256) void scan_c_kernel(int* __restrict__ off,
                                                     const int* __restrict__ bsum,
                                                     int N, int E) {
  int g = blockIdx.x * 256 + threadIdx.x;
  if (g < N) off[g] += bsum[g / SCAN_BS];
  if (g == 0) off[N] = E;
}

// Scatter edges into CSR slots; payload = (src, dinv[src] bitcast).
__global__ __launch_bounds__(256) void fill_kernel(const int* __restrict__ src,
                                                   const int* __restrict__ dst, int E,
                                                   const int* __restrict__ off,
                                                   int* __restrict__ cursor,
                                                   const float* __restrict__ dinv,
                                                   int2* __restrict__ csr) {
  int i = blockIdx.x * 256 + threadIdx.x;
  if (i >= E) return;
  int d = dst[i], s = src[i];
  int p = off[d] + atomicAdd(&cursor[d], 1);
  csr[p] = make_int2(s, __float_as_int(dinv[s]));
}

// C[M x NC](fp16) = A[M x K](fp32) @ W[K x NC](fp32).
// 128 x NC block tile, 256 threads, TM x TN (=8x8 or 8x4) per thread.
template <int K, int NC, int TM, int TN>
__global__ __launch_bounds__(256) void gemm_kernel(const float* __restrict__ A,
                                                   const float* __restrict__ W,
                                                   __half* __restrict__ C, int M) {
  constexpr int TX = NC / TN;    // 16
  constexpr int TY = 256 / TX;   // 16
  constexpr int BM = TY * TM;    // 128
  static_assert(BM == 128, "x-load mapping assumes BM==128");
  constexpr int WLD = (16 * NC) / 256;  // W floats per thread: 8 or 4
  __shared__ float xT[16][BM];  // [kk][row] transposed
  __shared__ float ws[16][NC];  // [kk][col]
  int row0 = blockIdx.x * BM;
  int t = threadIdx.x;
  int tx = t % TX, ty = t / TX;
  int lr = t >> 1;           // x-load row 0..127
  int lk = (t & 1) * 8;      // x-load k offset 0 or 8
  int wk = t >> 4;           // W-load k 0..15
  int wc = (t & 15) * WLD;   // W-load col
  float acc[TM][TN] = {};
  for (int k0 = 0; k0 < K; k0 += 16) {
    {
      int grow = row0 + lr;
      float4 v0 = make_float4(0.f, 0.f, 0.f, 0.f), v1 = v0;
      if (grow < M) {
        const float* ap = A + (size_t)grow * K + k0 + lk;
        v0 = *(const float4*)ap;
        v1 = *(const float4*)(ap + 4);
      }
      xT[lk + 0][lr] = v0.x; xT[lk + 1][lr] = v0.y;
      xT[lk + 2][lr] = v0.z; xT[lk + 3][lr] = v0.w;
      xT[lk + 4][lr] = v1.x; xT[lk + 5][lr] = v1.y;
      xT[lk + 6][lr] = v1.z; xT[lk + 7][lr] = v1.w;
    }
    {
      const float* wp = W + (size_t)(k0 + wk) * NC + wc;
      if constexpr (WLD == 8) {
        *(float4*)&ws[wk][wc] = *(const float4*)wp;
        *(float4*)&ws[wk][wc + 4] = *(const float4*)(wp + 4);
      } else {
        *(float4*)&ws[wk][wc] = *(const float4*)wp;
      }
    }
    __syncthreads();
#pragma unroll
    for (int kk = 0; kk < 16; kk++) {
      float a[TM], b[TN];
#pragma unroll
      for (int i = 0; i < TM; i += 4) *(float4*)&a[i] = *(const float4*)&xT[kk][ty * TM + i];
#pragma unroll
      for (int j = 0; j < TN; j += 4) *(float4*)&b[j] = *(const float4*)&ws[kk][tx * TN + j];
#pragma unroll
      for (int i = 0; i < TM; i++)
#pragma unroll
        for (int j = 0; j < TN; j++) acc[i][j] += a[i] * b[j];
    }
    __syncthreads();
  }
#pragma unroll
  for (int i = 0; i < TM; i++) {
    int row = row0 + ty * TM + i;
    if (row < M) {
      __half hv[TN];
#pragma unroll
      for (int j = 0; j < TN; j++) hv[j] = __float2half(acc[i][j]);
      if constexpr (TN == 8)
        *(int4*)(C + (size_t)row * NC + tx * TN) = *(const int4*)hv;
      else
        *(int2*)(C + (size_t)row * NC + tx * TN) = *(const int2*)hv;
    }
  }
}

// One wave per node: out[n,:] = dinv[n]*(sum_e w_e*h[src_e,:] + dinv[n]*h[n,:]) + b
// h is fp16; acc fp32. VW = halves per lane (NC = 64*VW).
template <int NC, int VW, bool RELU>
__global__ __launch_bounds__(256) void agg_kernel(const __half* __restrict__ h,
                                                  const int* __restrict__ off,
                                                  const int2* __restrict__ csr,
                                                  const float* __restrict__ dinv,
                                                  const float* __restrict__ bias,
                                                  float* __restrict__ out, int N) {
  int node = blockIdx.x * 4 + (threadIdx.x >> 6);
  int lane = threadIdx.x & 63;
  if (node >= N) return;
  int c = lane * VW;
  float di = dinv[node];
  float acc[VW];
  auto gather = [&](int sidx, float w) {
    if constexpr (VW == 2) {
      __half2 hv = *(const __half2*)(h + (size_t)sidx * NC + c);
      float2 f = __half22float2(hv);
      acc[0] += w * f.x;
      acc[1] += w * f.y;
    } else {
      acc[0] += w * __half2float(h[(size_t)sidx * NC + c]);
    }
  };
#pragma unroll
  for (int j = 0; j < VW; j++) acc[j] = 0.f;
  gather(node, di);  // self-loop (scaled by di again at the end)
  int e0 = off[node], e1 = off[node + 1];
  int e = e0;
  for (; e + 2 <= e1; e += 2) {  // unroll x2: two independent load chains
    int2 sw0 = csr[e];
    int2 sw1 = csr[e + 1];
    gather(sw0.x, __int_as_float(sw0.y));
    gather(sw1.x, __int_as_float(sw1.y));
  }
  if (e < e1) {
    int2 sw = csr[e];
    gather(sw.x, __int_as_float(sw.y));
  }
#pragma unroll
  for (int j = 0; j < VW; j++) {
    float r = di * acc[j] + bias[c + j];
    if (RELU) r = fmaxf(r, 0.f);
    out[(size_t)node * NC + c + j] = r;
  }
}

extern "C" void kernel_launch(void* const* d_in, const int* in_sizes, int n_in,
                              void* d_out, int out_size, void* d_ws, size_t ws_size,
                              hipStream_t stream) {
  const float* x  = (const float*)d_in[0];
  const int*   ei = (const int*)d_in[1];
  const float* W1 = (const float*)d_in[2];
  const float* b1 = (const float*)d_in[3];
  const float* W2 = (const float*)d_in[4];
  const float* b2 = (const float*)d_in[5];
  float* out = (float*)d_out;

  int N = in_sizes[0] / IN_DIM;
  int E = in_sizes[1] / 2;
  const int* src = ei;       // edge_index[0]
  const int* dst = ei + E;   // edge_index[1]

  char* p = (char*)d_ws;
  auto alloc = [&](size_t bytes) {
    char* q = p;
    p += (bytes + 255) & ~(size_t)255;
    return q;
  };
  int*    deg    = (int*)alloc((size_t)N * 4);
  float*  dinv   = (float*)alloc((size_t)N * 4);
  int*    off    = (int*)alloc((size_t)(N + 1) * 4);
  int*    bsum   = (int*)alloc(256 * 4);
  int*    cursor = (int*)alloc((size_t)N * 4);
  int2*   csr    = (int2*)alloc((size_t)E * 8);
  __half* h1     = (__half*)alloc((size_t)N * HID_DIM * 2);  // reused as h2
  float*  z      = (float*)alloc((size_t)N * HID_DIM * 4);
  __half* h2     = h1;
  (void)ws_size; (void)n_in; (void)out_size;

  hipMemsetAsync(deg, 0, (size_t)N * 4, stream);
  hipMemsetAsync(cursor, 0, (size_t)N * 4, stream);

  int eb = (E + 255) / 256;
  deg_kernel<<<eb, 256, 0, stream>>>(dst, E, deg);
  int nb = (N + SCAN_BS - 1) / SCAN_BS;  // 196 (<=256 required)
  scan_a_kernel<<<nb, SCAN_BS, 0, stream>>>(deg, N, off, bsum, dinv);
  scan_b_kernel<<<1, 256, 0, stream>>>(bsum, nb);
  scan_c_kernel<<<(N + 255) / 256, 256, 0, stream>>>(off, bsum, N, E);
  fill_kernel<<<eb, 256, 0, stream>>>(src, dst, E, off, cursor, dinv, csr);

  gemm_kernel<IN_DIM, HID_DIM, 8, 8><<<(N + 127) / 128, 256, 0, stream>>>(x, W1, h1, N);
  agg_kernel<HID_DIM, 2, true><<<(N + 3) / 4, 256, 0, stream>>>(h1, off, csr, dinv, b1, z, N);

  gemm_kernel<HID_DIM, OUT_DIM, 8, 4><<<(N + 127) / 128, 256, 0, stream>>>(z, W2, h2, N);
  agg_kernel<OUT_DIM, 1, false><<<(N + 3) / 4, 256, 0, stream>>>(h2, off, csr, dinv, b2, out, N);
}

// Round 3
// 538.700 us; speedup vs baseline: 1.3383x; 1.1263x over previous
//
#include <hip/hip_runtime.h>
#include <hip/hip_fp16.h>

// GCN: out = Ahat*(relu(Ahat*(x@W1)+b1))@W2 + b2,  Ahat = D^-1/2 (A+I) D^-1/2
// N=100000, E=1600000, IN=256, HID=128, OUT=64, fp32 in/out.
// R3: GEMMs moved to fp16 MFMA (v_mfma_f32_16x16x32_f16, fp32 acc).
//     W pre-transposed to fp16 W^T once; A staged fp32->fp16 in LDS with
//     +8-half row padding (2-way max bank aliasing = free). agg1 now emits
//     fp16 z so gemm2 reads fp16 directly. h1/h2 remain fp16 for the gather.

#define IN_DIM 256
#define HID_DIM 128
#define OUT_DIM 64
#define SCAN_BS 512

typedef _Float16 half8 __attribute__((ext_vector_type(8)));
typedef float floatx4 __attribute__((ext_vector_type(4)));

__global__ __launch_bounds__(256) void deg_kernel(const int* __restrict__ dst, int E,
                                                  int* __restrict__ deg) {
  int i = blockIdx.x * 256 + threadIdx.x;
  if (i < E) atomicAdd(&deg[dst[i]], 1);
}

__global__ __launch_bounds__(SCAN_BS) void scan_a_kernel(const int* __restrict__ deg, int N,
                                                         int* __restrict__ off,
                                                         int* __restrict__ bsum,
                                                         float* __restrict__ dinv) {
  __shared__ int sh[SCAN_BS];
  int t = threadIdx.x;
  int g = blockIdx.x * SCAN_BS + t;
  int v = (g < N) ? deg[g] : 0;
  if (g < N) dinv[g] = 1.0f / sqrtf((float)(v + 1));
  sh[t] = v;
  __syncthreads();
  for (int s = 1; s < SCAN_BS; s <<= 1) {
    int add = (t >= s) ? sh[t - s] : 0;
    __syncthreads();
    sh[t] += add;
    __syncthreads();
  }
  if (g < N) off[g] = sh[t] - v;
  if (t == SCAN_BS - 1) bsum[blockIdx.x] = sh[t];
}

__global__ __launch_bounds__(256) void scan_b_kernel(int* __restrict__ bsum, int nb) {
  __shared__ int sh[256];
  int t = threadIdx.x;
  int v = (t < nb) ? bsum[t] : 0;
  sh[t] = v;
  __syncthreads();
  for (int s = 1; s < 256; s <<= 1) {
    int add = (t >= s) ? sh[t - s] : 0;
    __syncthreads();
    sh[t] += add;
    __syncthreads();
  }
  if (t < nb) bsum[t] = sh[t] - v;
}

__global__ __launch_bounds__(256) void scan_c_kernel(int* __restrict__ off,
                                                     const int* __restrict__ bsum,
                                                     int N, int E) {
  int g = blockIdx.x * 256 + threadIdx.x;
  if (g < N) off[g] += bsum[g / SCAN_BS];
  if (g == 0) off[N] = E;
}

__global__ __launch_bounds__(256) void fill_kernel(const int* __restrict__ src,
                                                   const int* __restrict__ dst, int E,
                                                   const int* __restrict__ off,
                                                   int* __restrict__ cursor,
                                                   const float* __restrict__ dinv,
                                                   int2* __restrict__ csr) {
  int i = blockIdx.x * 256 + threadIdx.x;
  if (i >= E) return;
  int d = dst[i], s = src[i];
  int p = off[d] + atomicAdd(&cursor[d], 1);
  csr[p] = make_int2(s, __float_as_int(dinv[s]));
}

// Wt[n][k] = (half)W[k][n]; one thread per element of Wt.
__global__ __launch_bounds__(256) void wt_kernel(const float* __restrict__ W,
                                                 __half* __restrict__ Wt, int K, int NC) {
  int i = blockIdx.x * 256 + threadIdx.x;
  if (i >= K * NC) return;
  int n = i / K, k = i % K;
  Wt[i] = __float2half(W[k * NC + n]);
}

// C[M x NC](fp16) = A[M x K] @ W[K x NC] via v_mfma_f32_16x16x32_f16.
// A fp32 (converted in staging) or fp16. Wt = fp16 W^T [NC][K].
// 128-row block, 4 waves; wave w owns rows w*32..w*32+31 x all NC cols.
template <int K, int NC, typename AT>
__global__ __launch_bounds__(256) void mfma_gemm(const AT* __restrict__ A,
                                                 const __half* __restrict__ Wt,
                                                 __half* __restrict__ C, int M) {
  constexpr int BK = 32;
  constexpr int STR = BK + 8;  // padded LDS row stride (halves): 80B -> 2-way max
  constexpr int CT = NC / 16;  // col tiles per wave: 8 or 4
  __shared__ _Float16 As[128 * STR];
  __shared__ _Float16 Ws[NC * STR];
  int row0 = blockIdx.x * 128;
  int t = threadIdx.x;
  int wave = t >> 6, lane = t & 63, quad = lane >> 4, lr = lane & 15;
  floatx4 acc[2][CT] = {};

  // staging maps
  int arow = t >> 1, ako = (t & 1) * 16;  // 16 halves of A per thread
  int grow = row0 + arow;

  for (int k0 = 0; k0 < K; k0 += BK) {
    // ---- stage A (fp32 -> fp16, or fp16 copy) ----
    {
      half8 h0 = {}, h1 = {};
      if (grow < M) {
        if constexpr (sizeof(AT) == 4) {
          const float4* ap = (const float4*)(A + (size_t)grow * K + k0 + ako);
          float4 v0 = ap[0], v1 = ap[1], v2 = ap[2], v3 = ap[3];
          h0[0] = (_Float16)v0.x; h0[1] = (_Float16)v0.y;
          h0[2] = (_Float16)v0.z; h0[3] = (_Float16)v0.w;
          h0[4] = (_Float16)v1.x; h0[5] = (_Float16)v1.y;
          h0[6] = (_Float16)v1.z; h0[7] = (_Float16)v1.w;
          h1[0] = (_Float16)v2.x; h1[1] = (_Float16)v2.y;
          h1[2] = (_Float16)v2.z; h1[3] = (_Float16)v2.w;
          h1[4] = (_Float16)v3.x; h1[5] = (_Float16)v3.y;
          h1[6] = (_Float16)v3.z; h1[7] = (_Float16)v3.w;
        } else {
          const half8* ap = (const half8*)(A + (size_t)grow * K + k0 + ako);
          h0 = ap[0];
          h1 = ap[1];
        }
      }
      *(half8*)&As[arow * STR + ako] = h0;
      *(half8*)&As[arow * STR + ako + 8] = h1;
    }
    // ---- stage Wt tile [NC][BK] ----
    if constexpr (NC == 128) {
      int r = t >> 1, ko = (t & 1) * 16;
      const half8* wp = (const half8*)(Wt + (size_t)r * K + k0 + ko);
      *(half8*)&Ws[r * STR + ko] = wp[0];
      *(half8*)&Ws[r * STR + ko + 8] = wp[1];
    } else {  // NC == 64
      int r = t >> 2, ko = (t & 3) * 8;
      *(half8*)&Ws[r * STR + ko] = *(const half8*)(Wt + (size_t)r * K + k0 + ko);
    }
    __syncthreads();
    // ---- fragments + MFMA ----
    {
      int a_off = (wave * 32 + lr) * STR + quad * 8;
      half8 a0 = *(const half8*)&As[a_off];
      half8 a1 = *(const half8*)&As[a_off + 16 * STR];
      int b_off = lr * STR + quad * 8;
#pragma unroll
      for (int ct = 0; ct < CT; ct++) {
        half8 b = *(const half8*)&Ws[b_off + ct * 16 * STR];
        acc[0][ct] = __builtin_amdgcn_mfma_f32_16x16x32_f16(a0, b, acc[0][ct], 0, 0, 0);
        acc[1][ct] = __builtin_amdgcn_mfma_f32_16x16x32_f16(a1, b, acc[1][ct], 0, 0, 0);
      }
    }
    __syncthreads();
  }
  // ---- epilogue: C/D layout col=lane&15, row=quad*4+reg ----
#pragma unroll
  for (int rt = 0; rt < 2; rt++) {
    int rbase = row0 + wave * 32 + rt * 16 + quad * 4;
#pragma unroll
    for (int ct = 0; ct < CT; ct++) {
      int col = ct * 16 + lr;
#pragma unroll
      for (int i = 0; i < 4; i++) {
        int row = rbase + i;
        if (row < M) C[(size_t)row * NC + col] = __float2half(acc[rt][ct][i]);
      }
    }
  }
}

// One wave per node: out[n,:] = dinv[n]*(sum_e w_e*h[src_e,:] + dinv[n]*h[n,:]) + b
// h fp16, acc fp32, OT = output type (fp16 z or fp32 final out).
template <int NC, int VW, bool RELU, typename OT>
__global__ __launch_bounds__(256) void agg_kernel(const __half* __restrict__ h,
                                                  const int* __restrict__ off,
                                                  const int2* __restrict__ csr,
                                                  const float* __restrict__ dinv,
                                                  const float* __restrict__ bias,
                                                  OT* __restrict__ out, int N) {
  int node = blockIdx.x * 4 + (threadIdx.x >> 6);
  int lane = threadIdx.x & 63;
  if (node >= N) return;
  int c = lane * VW;
  float di = dinv[node];
  float acc[VW];
  auto gather = [&](int sidx, float w) {
    if constexpr (VW == 2) {
      __half2 hv = *(const __half2*)(h + (size_t)sidx * NC + c);
      float2 f = __half22float2(hv);
      acc[0] += w * f.x;
      acc[1] += w * f.y;
    } else {
      acc[0] += w * __half2float(h[(size_t)sidx * NC + c]);
    }
  };
#pragma unroll
  for (int j = 0; j < VW; j++) acc[j] = 0.f;
  gather(node, di);  // self-loop (scaled by di again at the end)
  int e0 = off[node], e1 = off[node + 1];
  int e = e0;
  for (; e + 2 <= e1; e += 2) {
    int2 sw0 = csr[e];
    int2 sw1 = csr[e + 1];
    gather(sw0.x, __int_as_float(sw0.y));
    gather(sw1.x, __int_as_float(sw1.y));
  }
  if (e < e1) {
    int2 sw = csr[e];
    gather(sw.x, __int_as_float(sw.y));
  }
  float r[VW];
#pragma unroll
  for (int j = 0; j < VW; j++) {
    r[j] = di * acc[j] + bias[c + j];
    if (RELU) r[j] = fmaxf(r[j], 0.f);
  }
  if constexpr (VW == 2 && sizeof(OT) == 2) {
    __half2 hv = __floats2half2_rn(r[0], r[1]);
    *(__half2*)((__half*)out + (size_t)node * NC + c) = hv;
  } else {
#pragma unroll
    for (int j = 0; j < VW; j++) out[(size_t)node * NC + c + j] = (OT)r[j];
  }
}

extern "C" void kernel_launch(void* const* d_in, const int* in_sizes, int n_in,
                              void* d_out, int out_size, void* d_ws, size_t ws_size,
                              hipStream_t stream) {
  const float* x  = (const float*)d_in[0];
  const int*   ei = (const int*)d_in[1];
  const float* W1 = (const float*)d_in[2];
  const float* b1 = (const float*)d_in[3];
  const float* W2 = (const float*)d_in[4];
  const float* b2 = (const float*)d_in[5];
  float* out = (float*)d_out;

  int N = in_sizes[0] / IN_DIM;
  int E = in_sizes[1] / 2;
  const int* src = ei;
  const int* dst = ei + E;

  char* p = (char*)d_ws;
  auto alloc = [&](size_t bytes) {
    char* q = p;
    p += (bytes + 255) & ~(size_t)255;
    return q;
  };
  int*    deg    = (int*)alloc((size_t)N * 4);
  float*  dinv   = (float*)alloc((size_t)N * 4);
  int*    off    = (int*)alloc((size_t)(N + 1) * 4);
  int*    bsum   = (int*)alloc(256 * 4);
  int*    cursor = (int*)alloc((size_t)N * 4);
  int2*   csr    = (int2*)alloc((size_t)E * 8);
  __half* h1     = (__half*)alloc((size_t)N * HID_DIM * 2);  // reused as h2
  __half* z16    = (__half*)alloc((size_t)N * HID_DIM * 2);
  __half* Wt1    = (__half*)alloc((size_t)IN_DIM * HID_DIM * 2);
  __half* Wt2    = (__half*)alloc((size_t)HID_DIM * OUT_DIM * 2);
  __half* h2     = h1;
  (void)ws_size; (void)n_in; (void)out_size;

  hipMemsetAsync(deg, 0, (size_t)N * 4, stream);
  hipMemsetAsync(cursor, 0, (size_t)N * 4, stream);

  int eb = (E + 255) / 256;
  deg_kernel<<<eb, 256, 0, stream>>>(dst, E, deg);
  int nb = (N + SCAN_BS - 1) / SCAN_BS;  // 196 (<=256 required)
  scan_a_kernel<<<nb, SCAN_BS, 0, stream>>>(deg, N, off, bsum, dinv);
  scan_b_kernel<<<1, 256, 0, stream>>>(bsum, nb);
  scan_c_kernel<<<(N + 255) / 256, 256, 0, stream>>>(off, bsum, N, E);
  fill_kernel<<<eb, 256, 0, stream>>>(src, dst, E, off, cursor, dinv, csr);
  wt_kernel<<<(IN_DIM * HID_DIM + 255) / 256, 256, 0, stream>>>(W1, Wt1, IN_DIM, HID_DIM);
  wt_kernel<<<(HID_DIM * OUT_DIM + 255) / 256, 256, 0, stream>>>(W2, Wt2, HID_DIM, OUT_DIM);

  int gb = (N + 127) / 128;
  mfma_gemm<IN_DIM, HID_DIM, float><<<gb, 256, 0, stream>>>(x, Wt1, h1, N);
  agg_kernel<HID_DIM, 2, true, __half><<<(N + 3) / 4, 256, 0, stream>>>(h1, off, csr, dinv, b1, z16, N);

  mfma_gemm<HID_DIM, OUT_DIM, __half><<<gb, 256, 0, stream>>>(z16, Wt2, h2, N);
  agg_kernel<OUT_DIM, 1, false, float><<<(N + 3) / 4, 256, 0, stream>>>(h2, off, csr, dinv, b2, out, N);
}

// Round 4
// 420.257 us; speedup vs baseline: 1.7154x; 1.2818x over previous
//
#include <hip/hip_runtime.h>
#include <hip/hip_fp16.h>

// GCN: out = Ahat*(relu(Ahat*(x@W1)+b1))@W2 + b2,  Ahat = D^-1/2 (A+I) D^-1/2
// N=100000, E=1600000, IN=256, HID=128, OUT=64, fp32 in/out.
// R4: CSR build rewritten as 2-level bucketed counting sort (bucket = dst>>7):
//     hist -> scan -> LDS-ranked scatter to bucket-contiguous pairs -> per-bucket
//     CSR/off/dinv via LDS atomics. Replaces ~3.2M device-scope returning
//     atomics + random 8B scatter (~300us) with ~45MB coalesced traffic.
//     CSR payload now src-only (4B); agg reads dinv[src] (L2 broadcast).
//     agg edge loop unrolled x4. GEMMs stay fp16 MFMA (R3).

#define IN_DIM 256
#define HID_DIM 128
#define OUT_DIM 64
#define BSHIFT 7
#define MAXNB 1024  // supports N <= 131072

typedef _Float16 half8 __attribute__((ext_vector_type(8)));
typedef float floatx4 __attribute__((ext_vector_type(4)));

// ---- build stage A: global bucket histogram (LDS-privatized) ----
__global__ __launch_bounds__(256) void bucket_hist(const int* __restrict__ dst, int E,
                                                   int NB, int* __restrict__ bcnt) {
  __shared__ int h[MAXNB];
  for (int i = threadIdx.x; i < MAXNB; i += 256) h[i] = 0;
  __syncthreads();
  for (int i = blockIdx.x * 256 + threadIdx.x; i < E; i += gridDim.x * 256)
    atomicAdd(&h[dst[i] >> BSHIFT], 1);
  __syncthreads();
  for (int i = threadIdx.x; i < NB; i += 256) {
    int v = h[i];
    if (v) atomicAdd(&bcnt[i], v);
  }
}

// ---- build stage B: scan bucket counts; init cursors; off[N]=E ----
__global__ __launch_bounds__(1024) void bucket_scan(const int* __restrict__ bcnt, int NB,
                                                    int E, int* __restrict__ boff,
                                                    int* __restrict__ bcur,
                                                    int* __restrict__ off, int N) {
  __shared__ int sh[1024];
  int t = threadIdx.x;
  int v = (t < NB) ? bcnt[t] : 0;
  sh[t] = v;
  __syncthreads();
  for (int s = 1; s < 1024; s <<= 1) {
    int a = (t >= s) ? sh[t - s] : 0;
    __syncthreads();
    sh[t] += a;
    __syncthreads();
  }
  if (t < NB) {
    int ex = sh[t] - v;
    boff[t] = ex;
    bcur[t] = ex;
  }
  if (t == 0) {
    boff[NB] = E;
    off[N] = E;
  }
}

// ---- build stage C: scatter edges into bucket-contiguous pairs (src,dst) ----
__global__ __launch_bounds__(256) void bucket_scatter(const int* __restrict__ src,
                                                      const int* __restrict__ dst, int E,
                                                      int NB, int* __restrict__ bcur,
                                                      int2* __restrict__ pairs) {
  __shared__ int h[MAXNB], base[MAXNB], cur[MAXNB];
  int t = threadIdx.x;
  for (int i = t; i < MAXNB; i += 256) h[i] = 0;
  __syncthreads();
  int chunk = (E + gridDim.x - 1) / gridDim.x;
  int s0 = blockIdx.x * chunk, s1 = min(E, s0 + chunk);
  for (int i = s0 + t; i < s1; i += 256) atomicAdd(&h[dst[i] >> BSHIFT], 1);
  __syncthreads();
  for (int i = t; i < NB; i += 256) {
    int c = h[i];
    base[i] = c ? atomicAdd(&bcur[i], c) : 0;
    cur[i] = 0;
  }
  __syncthreads();
  for (int i = s0 + t; i < s1; i += 256) {
    int d = dst[i];
    int b = d >> BSHIFT;
    int r = atomicAdd(&cur[b], 1);
    pairs[base[b] + r] = make_int2(src[i], d);
  }
}

// ---- build stage D: per-bucket local counting sort -> csr/off/dinv ----
__global__ __launch_bounds__(256) void bucket_csr(const int2* __restrict__ pairs,
                                                  const int* __restrict__ boff, int N,
                                                  int* __restrict__ csr,
                                                  int* __restrict__ off,
                                                  float* __restrict__ dinv) {
  int b = blockIdx.x;
  int t = threadIdx.x;
  int n0 = b << BSHIFT;
  int cnt = min(128, N - n0);
  __shared__ int ldeg[128], sh[128], lcur[128];
  if (t < 128) ldeg[t] = 0;
  __syncthreads();
  int e0 = boff[b], e1 = boff[b + 1];
  for (int e = e0 + t; e < e1; e += 256) atomicAdd(&ldeg[pairs[e].y - n0], 1);
  __syncthreads();
  int v = (t < 128) ? ldeg[t] : 0;
  if (t < 128) sh[t] = v;
  __syncthreads();
  for (int s = 1; s < 128; s <<= 1) {
    int a = (t < 128 && t >= s) ? sh[t - s] : 0;
    __syncthreads();
    if (t < 128) sh[t] += a;
    __syncthreads();
  }
  if (t < cnt) {
    int ex = sh[t] - v;
    off[n0 + t] = e0 + ex;
    dinv[n0 + t] = 1.0f / sqrtf((float)(v + 1));
    lcur[t] = ex;  // cursor starts at exclusive offset
  }
  __syncthreads();
  for (int e = e0 + t; e < e1; e += 256) {
    int2 pr = pairs[e];
    int d = pr.y - n0;
    int r = atomicAdd(&lcur[d], 1);
    csr[e0 + r] = pr.x;
  }
}

// Wt[n][k] = (half)W[k][n]
__global__ __launch_bounds__(256) void wt_kernel(const float* __restrict__ W,
                                                 __half* __restrict__ Wt, int K, int NC) {
  int i = blockIdx.x * 256 + threadIdx.x;
  if (i >= K * NC) return;
  int n = i / K, k = i % K;
  Wt[i] = __float2half(W[k * NC + n]);
}

// C[M x NC](fp16) = A[M x K] @ W[K x NC] via v_mfma_f32_16x16x32_f16.
template <int K, int NC, typename AT>
__global__ __launch_bounds__(256) void mfma_gemm(const AT* __restrict__ A,
                                                 const __half* __restrict__ Wt,
                                                 __half* __restrict__ C, int M) {
  constexpr int BK = 32;
  constexpr int STR = BK + 8;  // padded LDS row stride (halves) -> 2-way max
  constexpr int CT = NC / 16;
  __shared__ _Float16 As[128 * STR];
  __shared__ _Float16 Ws[NC * STR];
  int row0 = blockIdx.x * 128;
  int t = threadIdx.x;
  int wave = t >> 6, lane = t & 63, quad = lane >> 4, lr = lane & 15;
  floatx4 acc[2][CT] = {};
  int arow = t >> 1, ako = (t & 1) * 16;
  int grow = row0 + arow;

  for (int k0 = 0; k0 < K; k0 += BK) {
    {
      half8 h0 = {}, h1 = {};
      if (grow < M) {
        if constexpr (sizeof(AT) == 4) {
          const float4* ap = (const float4*)(A + (size_t)grow * K + k0 + ako);
          float4 v0 = ap[0], v1 = ap[1], v2 = ap[2], v3 = ap[3];
          h0[0] = (_Float16)v0.x; h0[1] = (_Float16)v0.y;
          h0[2] = (_Float16)v0.z; h0[3] = (_Float16)v0.w;
          h0[4] = (_Float16)v1.x; h0[5] = (_Float16)v1.y;
          h0[6] = (_Float16)v1.z; h0[7] = (_Float16)v1.w;
          h1[0] = (_Float16)v2.x; h1[1] = (_Float16)v2.y;
          h1[2] = (_Float16)v2.z; h1[3] = (_Float16)v2.w;
          h1[4] = (_Float16)v3.x; h1[5] = (_Float16)v3.y;
          h1[6] = (_Float16)v3.z; h1[7] = (_Float16)v3.w;
        } else {
          const half8* ap = (const half8*)(A + (size_t)grow * K + k0 + ako);
          h0 = ap[0];
          h1 = ap[1];
        }
      }
      *(half8*)&As[arow * STR + ako] = h0;
      *(half8*)&As[arow * STR + ako + 8] = h1;
    }
    if constexpr (NC == 128) {
      int r = t >> 1, ko = (t & 1) * 16;
      const half8* wp = (const half8*)(Wt + (size_t)r * K + k0 + ko);
      *(half8*)&Ws[r * STR + ko] = wp[0];
      *(half8*)&Ws[r * STR + ko + 8] = wp[1];
    } else {  // NC == 64
      int r = t >> 2, ko = (t & 3) * 8;
      *(half8*)&Ws[r * STR + ko] = *(const half8*)(Wt + (size_t)r * K + k0 + ko);
    }
    __syncthreads();
    {
      int a_off = (wave * 32 + lr) * STR + quad * 8;
      half8 a0 = *(const half8*)&As[a_off];
      half8 a1 = *(const half8*)&As[a_off + 16 * STR];
      int b_off = lr * STR + quad * 8;
#pragma unroll
      for (int ct = 0; ct < CT; ct++) {
        half8 bfr = *(const half8*)&Ws[b_off + ct * 16 * STR];
        acc[0][ct] = __builtin_amdgcn_mfma_f32_16x16x32_f16(a0, bfr, acc[0][ct], 0, 0, 0);
        acc[1][ct] = __builtin_amdgcn_mfma_f32_16x16x32_f16(a1, bfr, acc[1][ct], 0, 0, 0);
      }
    }
    __syncthreads();
  }
#pragma unroll
  for (int rt = 0; rt < 2; rt++) {
    int rbase = row0 + wave * 32 + rt * 16 + quad * 4;
#pragma unroll
    for (int ct = 0; ct < CT; ct++) {
      int col = ct * 16 + lr;
#pragma unroll
      for (int i = 0; i < 4; i++) {
        int row = rbase + i;
        if (row < M) C[(size_t)row * NC + col] = __float2half(acc[rt][ct][i]);
      }
    }
  }
}

// One wave per node: out[n,:] = dinv[n]*(sum_e dinv[src]*h[src,:] + dinv[n]*h[n,:]) + b
template <int NC, int VW, bool RELU, typename OT>
__global__ __launch_bounds__(256) void agg_kernel(const __half* __restrict__ h,
                                                  const int* __restrict__ off,
                                                  const int* __restrict__ csr,
                                                  const float* __restrict__ dinv,
                                                  const float* __restrict__ bias,
                                                  OT* __restrict__ out, int N) {
  int node = blockIdx.x * 4 + (threadIdx.x >> 6);
  int lane = threadIdx.x & 63;
  if (node >= N) return;
  int c = lane * VW;
  float di = dinv[node];
  float acc[VW];
  auto gather = [&](int sidx, float w) {
    if constexpr (VW == 2) {
      __half2 hv = *(const __half2*)(h + (size_t)sidx * NC + c);
      float2 f = __half22float2(hv);
      acc[0] += w * f.x;
      acc[1] += w * f.y;
    } else {
      acc[0] += w * __half2float(h[(size_t)sidx * NC + c]);
    }
  };
#pragma unroll
  for (int j = 0; j < VW; j++) acc[j] = 0.f;
  gather(node, di);  // self-loop (x di again at the end)
  int e0 = off[node], e1 = off[node + 1];
  int e = e0;
  for (; e + 4 <= e1; e += 4) {  // 4 independent gather chains
    int s0 = csr[e], s1 = csr[e + 1], s2 = csr[e + 2], s3 = csr[e + 3];
    float w0 = dinv[s0], w1 = dinv[s1], w2 = dinv[s2], w3 = dinv[s3];
    gather(s0, w0);
    gather(s1, w1);
    gather(s2, w2);
    gather(s3, w3);
  }
  for (; e < e1; e++) {
    int s = csr[e];
    gather(s, dinv[s]);
  }
  float r[VW];
#pragma unroll
  for (int j = 0; j < VW; j++) {
    r[j] = di * acc[j] + bias[c + j];
    if (RELU) r[j] = fmaxf(r[j], 0.f);
  }
  if constexpr (VW == 2 && sizeof(OT) == 2) {
    __half2 hv = __floats2half2_rn(r[0], r[1]);
    *(__half2*)((__half*)out + (size_t)node * NC + c) = hv;
  } else {
#pragma unroll
    for (int j = 0; j < VW; j++) out[(size_t)node * NC + c + j] = (OT)r[j];
  }
}

extern "C" void kernel_launch(void* const* d_in, const int* in_sizes, int n_in,
                              void* d_out, int out_size, void* d_ws, size_t ws_size,
                              hipStream_t stream) {
  const float* x  = (const float*)d_in[0];
  const int*   ei = (const int*)d_in[1];
  const float* W1 = (const float*)d_in[2];
  const float* b1 = (const float*)d_in[3];
  const float* W2 = (const float*)d_in[4];
  const float* b2 = (const float*)d_in[5];
  float* out = (float*)d_out;

  int N = in_sizes[0] / IN_DIM;
  int E = in_sizes[1] / 2;
  const int* src = ei;
  const int* dst = ei + E;
  int NB = (N + 127) >> BSHIFT;  // 782 for N=100000 (must be <= MAXNB)

  char* p = (char*)d_ws;
  auto alloc = [&](size_t bytes) {
    char* q = p;
    p += (bytes + 255) & ~(size_t)255;
    return q;
  };
  int*    bcnt  = (int*)alloc((size_t)NB * 4);
  int*    boff  = (int*)alloc((size_t)(NB + 1) * 4);
  int*    bcur  = (int*)alloc((size_t)NB * 4);
  int2*   pairs = (int2*)alloc((size_t)E * 8);
  int*    csr   = (int*)alloc((size_t)E * 4);
  int*    off   = (int*)alloc((size_t)(N + 1) * 4);
  float*  dinv  = (float*)alloc((size_t)N * 4);
  __half* h1    = (__half*)alloc((size_t)N * HID_DIM * 2);  // reused as h2
  __half* z16   = (__half*)alloc((size_t)N * HID_DIM * 2);
  __half* Wt1   = (__half*)alloc((size_t)IN_DIM * HID_DIM * 2);
  __half* Wt2   = (__half*)alloc((size_t)HID_DIM * OUT_DIM * 2);
  __half* h2    = h1;
  (void)ws_size; (void)n_in; (void)out_size;

  hipMemsetAsync(bcnt, 0, (size_t)NB * 4, stream);

  bucket_hist<<<256, 256, 0, stream>>>(dst, E, NB, bcnt);
  bucket_scan<<<1, 1024, 0, stream>>>(bcnt, NB, E, boff, bcur, off, N);
  bucket_scatter<<<256, 256, 0, stream>>>(src, dst, E, NB, bcur, pairs);
  bucket_csr<<<NB, 256, 0, stream>>>(pairs, boff, N, csr, off, dinv);
  wt_kernel<<<(IN_DIM * HID_DIM + 255) / 256, 256, 0, stream>>>(W1, Wt1, IN_DIM, HID_DIM);
  wt_kernel<<<(HID_DIM * OUT_DIM + 255) / 256, 256, 0, stream>>>(W2, Wt2, HID_DIM, OUT_DIM);

  int gb = (N + 127) / 128;
  mfma_gemm<IN_DIM, HID_DIM, float><<<gb, 256, 0, stream>>>(x, Wt1, h1, N);
  agg_kernel<HID_DIM, 2, true, __half><<<(N + 3) / 4, 256, 0, stream>>>(h1, off, csr, dinv, b1, z16, N);

  mfma_gemm<HID_DIM, OUT_DIM, __half><<<gb, 256, 0, stream>>>(z16, Wt2, h2, N);
  agg_kernel<OUT_DIM, 1, false, float><<<(N + 3) / 4, 256, 0, stream>>>(h2, off, csr, dinv, b2, out, N);
}